// Round 6
// baseline (6484.246 us; speedup 1.0000x reference)
//
#include <hip/hip_runtime.h>
#include <hip/hip_cooperative_groups.h>

namespace cg = cooperative_groups;

#define SWZ(row, kb) ((kb) ^ (((row)&7)<<4))

typedef _Float16 f16x8 __attribute__((ext_vector_type(8)));
typedef float f32x4 __attribute__((ext_vector_type(4)));

__device__ inline void mfma_f16(f32x4& acc, f16x8 a, f16x8 b){
  acc = __builtin_amdgcn_mfma_f32_16x16x32_f16(a, b, acc, 0, 0, 0);
}
__device__ inline unsigned short f2h(float f){
  union{_Float16 h; unsigned short s;} u; u.h = (_Float16)f; return u.s;
}
__device__ inline float sigm(float x){
  float e = __expf(-x);
  return __builtin_amdgcn_rcpf(1.f + e);
}
__device__ inline float tanh_(float x){
  float e = __expf(2.f*x);
  return 1.f - 2.f*__builtin_amdgcn_rcpf(e + 1.f);
}

struct P8 { const float* p[8]; };
struct P4 { const float* p[4]; };

// ---- K1: transpose+convert weights -> [n'][1024] fp16 ----
// n' = (j>>4)*64 + (j&15)*4 + gate
__global__ void k_transpose_w(P8 srcs, unsigned short* __restrict__ wx_t,
                              unsigned short* __restrict__ wh_t){
  __shared__ float tile[32][33];
  int z = blockIdx.z;               // which*4 + gate
  int gate = z & 3, which = z >> 2;
  const float* src = srcs.p[z];
  unsigned short* dst = which ? wh_t : wx_t;
  int k0 = blockIdx.x*32, j0 = blockIdx.y*32;
  int tx = threadIdx.x, ty = threadIdx.y;   // 32 x 8
  #pragma unroll
  for (int s=0; s<4; s++){
    int k = ty*4 + s;
    tile[k][tx] = src[(size_t)(k0+k)*1024 + j0 + tx];
  }
  __syncthreads();
  #pragma unroll
  for (int s=0; s<4; s++){
    int j = j0 + ty*4 + s;
    int np = ((j>>4)<<6) + ((j&15)<<2) + gate;
    dst[(size_t)np*1024 + k0 + tx] = f2h(tile[tx][ty*4+s]);
  }
}

// ---- K1b: combined bias[n'] ----
__global__ void k_bias(P4 bs, float* __restrict__ bias_c){
  int np = blockIdx.x*blockDim.x + threadIdx.x;
  if (np >= 4096) return;
  int gate = np & 3;
  int j = ((np>>6)<<4) + ((np>>2)&15);
  bias_c[np] = bs.p[gate][j];
}

// ---- K2: phase-1 GEMM  XP = fp16(x) @ fp16(Wx) + bias ----
// out: XP[t][jg][b][nc] as i16 fixed-point (value * 4096)
__global__ __launch_bounds__(256) void k_gemm_xp(
    const float* __restrict__ X,
    const unsigned short* __restrict__ Wt,
    const float* __restrict__ bias_c,
    short* __restrict__ XP)
{
  __shared__ unsigned short lds_a[128*64];
  __shared__ unsigned short lds_b0[128*64];
  const int tid = threadIdx.x;
  const int m0 = blockIdx.y*128, n0 = blockIdx.x*128;
  const int w = tid>>6, l = tid&63;
  const int wr = w>>1, wc = w&1;
  const int lr = l&15, lk = (l>>4)*16;
  f32x4 acc[4][4] = {};
  for (int kt=0; kt<16; kt++){
    __syncthreads();
    const int kb = kt*64;
    #pragma unroll
    for (int c4=0; c4<4; c4++){
      int idx = c4*256 + tid;
      int row = idx>>3, cb = idx&7;
      const float* sa = X + (size_t)(m0+row)*1024 + kb + cb*8;
      float4 f0 = *(const float4*)sa;
      float4 f1 = *(const float4*)(sa+4);
      f16x8 av;
      av[0]=(_Float16)f0.x; av[1]=(_Float16)f0.y; av[2]=(_Float16)f0.z; av[3]=(_Float16)f0.w;
      av[4]=(_Float16)f1.x; av[5]=(_Float16)f1.y; av[6]=(_Float16)f1.z; av[7]=(_Float16)f1.w;
      *(f16x8*)((char*)lds_a + row*128 + SWZ(row, cb*16)) = av;
      *(f16x8*)((char*)lds_b0 + row*128 + SWZ(row, cb*16)) =
        *(const f16x8*)(Wt + (size_t)(n0+row)*1024 + kb + cb*8);
    }
    __syncthreads();
    #pragma unroll
    for (int kk=0; kk<2; kk++){
      f16x8 af[4], b0[4];
      #pragma unroll
      for (int tm=0; tm<4; tm++){
        int row = wr*64 + tm*16 + lr;
        af[tm] = *(const f16x8*)((char*)lds_a + row*128 + SWZ(row, kk*64 + lk));
      }
      #pragma unroll
      for (int tn=0; tn<4; tn++){
        int row = wc*64 + tn*16 + lr;
        b0[tn] = *(const f16x8*)((char*)lds_b0 + row*128 + SWZ(row, kk*64 + lk));
      }
      #pragma unroll
      for (int tm=0; tm<4; tm++)
        #pragma unroll
        for (int tn=0; tn<4; tn++)
          mfma_f16(acc[tm][tn], af[tm], b0[tn]);
    }
  }
  #pragma unroll
  for (int tm=0; tm<4; tm++)
    for (int tn=0; tn<4; tn++)
      for (int r=0; r<4; r++){
        int ml = wr*64 + tm*16 + ((l>>4)<<2) + r;
        int nl = wc*64 + tn*16 + lr;
        int m = m0 + ml, np = n0 + nl;
        int t = m & 255, b = m >> 8, jg = np >> 6, nc = np & 63;
        size_t idx = (((size_t)t*64 + jg)*64 + b)*64 + nc;
        float v = (acc[tm][tn][r] + bias_c[np]) * 4096.f;
        v = fminf(fmaxf(v, -32767.f), 32767.f);
        XP[idx] = (short)(int)rintf(v);
      }
}

// ---- K3: persistent scan (flag-based cross-WG sync) ----
// 128 WGs = 2 bg x 64 jg, 512 thr (8 waves = 2 mh x 4 nh). WG owns 32 batches x 16 j.
__global__ __launch_bounds__(512) void k_scan(
    const unsigned short* __restrict__ Wh_t,
    const short* __restrict__ XPq,
    unsigned short* __restrict__ hb0, unsigned short* __restrict__ hb1,
    unsigned int* __restrict__ flags, float* __restrict__ dout)
{
  __shared__ unsigned short lds_w[64*1024];  // 128 KB weights (swizzled)
  __shared__ unsigned short lds_h[32*256];   // 16 KB h k-quarter stage (swizzled)
  __shared__ float lds_g[32*64];             // 8 KB gate pre-activations
  __shared__ unsigned short lds_ho[32*16];   // 1 KB h out
  const int tid = threadIdx.x;
  const int wgid = blockIdx.x;
  const int bg = wgid >> 6, jg = wgid & 63;

  for (int s=0; s<16; s++){
    int idx = s*512 + tid;            // 8192 16B-chunks
    int row = idx>>7, cb = idx&127;
    *(f16x8*)((char*)lds_w + row*2048 + SWZ(row, cb*16)) =
      *(const f16x8*)(Wh_t + (size_t)(jg*64+row)*1024 + cb*8);
  }
  const int w = tid>>6, l = tid&63;
  const int mh = w>>2, nh = w&3;
  const int lr = l&15, lkb = (l>>4)*16;
  const int arow = mh*16 + lr;
  const char* abase = (const char*)lds_h + arow*512;
  const int aswz = (arow&7)<<4;
  const int wrow = nh*16 + lr;
  const char* wbase = (const char*)lds_w + wrow*2048;
  const int wswz = (wrow&7)<<4;
  const int b_l = tid>>4, jr = tid&15;
  float c = 0.f;
  __syncthreads();

  for (int t=0; t<256; t++){
    const unsigned short* cur = (t&1) ? hb1 : hb0;
    unsigned short* nxt = (t&1) ? hb0 : hb1;
    // preload this step's XP (independent of h) so latency hides under MFMA
    size_t xidx = (((size_t)t*64 + jg)*64 + (bg*32 + b_l))*64 + jr*4;
    short4 qv = *(const short4*)(XPq + xidx);
    f32x4 acc0 = {0,0,0,0}, acc1 = {0,0,0,0};
    for (int q=0; q<4; q++){
      #pragma unroll
      for (int s=0; s<4; s++){
        int idx = s*512 + tid;        // 2048 8B-chunks
        int row = idx>>6, cb = idx&63;
        unsigned long long v = __hip_atomic_load(
            (const unsigned long long*)(cur + (size_t)(bg*32+row)*1024 + q*256 + cb*4),
            __ATOMIC_RELAXED, __HIP_MEMORY_SCOPE_AGENT);
        *(unsigned long long*)((char*)lds_h + row*512 + SWZ(row, cb*8)) = v;
      }
      __syncthreads();
      #pragma unroll
      for (int kk=0; kk<8; kk++){
        f16x8 a = *(const f16x8*)(abase + ((kk*64 + lkb) ^ aswz));
        int kb = (q*8 + kk)*64 + lkb;
        f16x8 b = *(const f16x8*)(wbase + (kb ^ wswz));
        if (kk & 1) mfma_f16(acc1, a, b); else mfma_f16(acc0, a, b);
      }
      __syncthreads();
    }
    f32x4 acc = acc0 + acc1;
    {
      int row = mh*16 + ((l>>4)<<2);
      #pragma unroll
      for (int r=0; r<4; r++) lds_g[(row+r)*64 + nh*16 + lr] = acc[r];
    }
    __syncthreads();
    // elementwise: thread <-> (b_l, jr); nc = jr*4 + gate
    {
      const float INV = 1.f/4096.f;
      float p0 = lds_g[b_l*64 + jr*4 + 0] + (float)qv.x * INV;
      float p1 = lds_g[b_l*64 + jr*4 + 1] + (float)qv.y * INV;
      float p2 = lds_g[b_l*64 + jr*4 + 2] + (float)qv.z * INV;
      float p3 = lds_g[b_l*64 + jr*4 + 3] + (float)qv.w * INV;
      float f = sigm(p0), ii = sigm(p1), o = sigm(p2), g = tanh_(p3);
      c = f*c + ii*g;
      float hn = o * tanh_(c);
      lds_ho[b_l*16 + jr] = f2h(hn);
      if (t == 255) dout[(size_t)(bg*32 + b_l)*1024 + jg*16 + jr] = hn;
    }
    __syncthreads();
    if (tid < 128){
      int b = tid>>2, part = tid&3;
      unsigned long long v = ((const unsigned long long*)lds_ho)[tid];
      __hip_atomic_store((unsigned long long*)(nxt + (size_t)(bg*32+b)*1024 + jg*16 + part*4),
                         v, __ATOMIC_RELAXED, __HIP_MEMORY_SCOPE_AGENT);
    }
    __syncthreads();   // vmcnt-drain: all waves' h stores complete before flag
    if (t < 255){
      if (tid == 0)
        __hip_atomic_store(&flags[wgid], (unsigned)(t+1),
                           __ATOMIC_RELEASE, __HIP_MEMORY_SCOPE_AGENT);
      if (tid < 64){
        const unsigned* fp = flags + bg*64 + tid;
        while (true){
          unsigned v = __hip_atomic_load(fp, __ATOMIC_RELAXED, __HIP_MEMORY_SCOPE_AGENT);
          if (__all((int)(v > (unsigned)t))) break;
          __builtin_amdgcn_s_sleep(1);
        }
        __builtin_amdgcn_fence(__ATOMIC_ACQUIRE, "agent");
      }
      __threadfence();
      __syncthreads();
    }
  }
}

extern "C" void kernel_launch(void* const* d_in, const int* in_sizes, int n_in,
                              void* d_out, int out_size, void* d_ws, size_t ws_size,
                              hipStream_t stream){
  const float* inp = (const float*)d_in[0];
  P8 pw; P4 pb;
  // gate order: 0=f 1=i 2=o 3=c
  pw.p[0] = (const float*)d_in[1];  pw.p[1] = (const float*)d_in[4];
  pw.p[2] = (const float*)d_in[7];  pw.p[3] = (const float*)d_in[10];
  pw.p[4] = (const float*)d_in[2];  pw.p[5] = (const float*)d_in[5];
  pw.p[6] = (const float*)d_in[8];  pw.p[7] = (const float*)d_in[11];
  pb.p[0] = (const float*)d_in[3];  pb.p[1] = (const float*)d_in[6];
  pb.p[2] = (const float*)d_in[9];  pb.p[3] = (const float*)d_in[12];
  float* out = (float*)d_out;
  char* ws = (char*)d_ws;

  const size_t off_flags = 0;
  const size_t off_hb0  = 4096;
  const size_t off_hb1  = off_hb0 + 131072;
  const size_t off_bias = off_hb1 + 131072;
  const size_t off_wxt  = off_bias + 16384;
  const size_t off_wht  = off_wxt + 8388608ull;    // Wx' [4096][1024] f16
  const size_t off_xp   = off_wht + 8388608ull;    // Wh' [4096][1024] f16
  const size_t xp_elems = 256ull*64*64*64;         // 67,108,864 i16
  const size_t need = off_xp + xp_elems*2;         // ~151 MB

  if (ws_size < need){
    hipMemsetAsync(d_out, 0, (size_t)out_size*4, stream);
    return;
  }

  unsigned* flags = (unsigned*)(ws + off_flags);
  unsigned short* hb0 = (unsigned short*)(ws + off_hb0);
  unsigned short* hb1 = (unsigned short*)(ws + off_hb1);
  float* bias_c = (float*)(ws + off_bias);
  unsigned short* Wxt = (unsigned short*)(ws + off_wxt);
  unsigned short* Wht = (unsigned short*)(ws + off_wht);
  short* XPq = (short*)(ws + off_xp);

  hipMemsetAsync(ws, 0, off_bias, stream);   // flags + h buffers
  k_transpose_w<<<dim3(32,32,8), dim3(32,8), 0, stream>>>(pw, Wxt, Wht);
  k_bias<<<16, 256, 0, stream>>>(pb, bias_c);
  k_gemm_xp<<<dim3(32,128), 256, 0, stream>>>(inp, Wxt, bias_c, XPq);

  void* args[6] = {(void*)&Wht, (void*)&XPq, (void*)&hb0, (void*)&hb1,
                   (void*)&flags, (void*)&out};
  hipLaunchCooperativeKernel((void*)k_scan, dim3(128), dim3(512), args, 0u, stream);
}

// Round 7
// 2781.595 us; speedup vs baseline: 2.3311x; 2.3311x over previous
//
#include <hip/hip_runtime.h>
#include <hip/hip_cooperative_groups.h>

namespace cg = cooperative_groups;

#define SWZ(row, kb) ((kb) ^ (((row)&7)<<4))

typedef _Float16 f16x8 __attribute__((ext_vector_type(8)));
typedef float f32x4 __attribute__((ext_vector_type(4)));

__device__ inline void mfma_f16(f32x4& acc, f16x8 a, f16x8 b){
  acc = __builtin_amdgcn_mfma_f32_16x16x32_f16(a, b, acc, 0, 0, 0);
}
__device__ inline unsigned short f2h(float f){
  union{_Float16 h; unsigned short s;} u; u.h = (_Float16)f; return u.s;
}
__device__ inline float sigm(float x){
  float e = __expf(-x);
  return __builtin_amdgcn_rcpf(1.f + e);
}
__device__ inline float tanh_(float x){
  float e = __expf(2.f*x);
  return 1.f - 2.f*__builtin_amdgcn_rcpf(e + 1.f);
}

struct P8 { const float* p[8]; };
struct P4 { const float* p[4]; };

// ---- K1: transpose+convert weights -> [n'][1024] fp16 ----
// n' = (j>>4)*64 + (j&15)*4 + gate
__global__ void k_transpose_w(P8 srcs, unsigned short* __restrict__ wx_t,
                              unsigned short* __restrict__ wh_t){
  __shared__ float tile[32][33];
  int z = blockIdx.z;               // which*4 + gate
  int gate = z & 3, which = z >> 2;
  const float* src = srcs.p[z];
  unsigned short* dst = which ? wh_t : wx_t;
  int k0 = blockIdx.x*32, j0 = blockIdx.y*32;
  int tx = threadIdx.x, ty = threadIdx.y;   // 32 x 8
  #pragma unroll
  for (int s=0; s<4; s++){
    int k = ty*4 + s;
    tile[k][tx] = src[(size_t)(k0+k)*1024 + j0 + tx];
  }
  __syncthreads();
  #pragma unroll
  for (int s=0; s<4; s++){
    int j = j0 + ty*4 + s;
    int np = ((j>>4)<<6) + ((j&15)<<2) + gate;
    dst[(size_t)np*1024 + k0 + tx] = f2h(tile[tx][ty*4+s]);
  }
}

// ---- K1b: combined bias[n'] ----
__global__ void k_bias(P4 bs, float* __restrict__ bias_c){
  int np = blockIdx.x*blockDim.x + threadIdx.x;
  if (np >= 4096) return;
  int gate = np & 3;
  int j = ((np>>6)<<4) + ((np>>2)&15);
  bias_c[np] = bs.p[gate][j];
}

// ---- K2: phase-1 GEMM  XP = fp16(x) @ fp16(Wx) + bias ----
// out: XP[t][jg][b][nc] as i16 fixed-point (value * 4096)
__global__ __launch_bounds__(256) void k_gemm_xp(
    const float* __restrict__ X,
    const unsigned short* __restrict__ Wt,
    const float* __restrict__ bias_c,
    short* __restrict__ XP)
{
  __shared__ unsigned short lds_a[128*64];
  __shared__ unsigned short lds_b0[128*64];
  const int tid = threadIdx.x;
  const int m0 = blockIdx.y*128, n0 = blockIdx.x*128;
  const int w = tid>>6, l = tid&63;
  const int wr = w>>1, wc = w&1;
  const int lr = l&15, lk = (l>>4)*16;
  f32x4 acc[4][4] = {};
  for (int kt=0; kt<16; kt++){
    __syncthreads();
    const int kb = kt*64;
    #pragma unroll
    for (int c4=0; c4<4; c4++){
      int idx = c4*256 + tid;
      int row = idx>>3, cb = idx&7;
      const float* sa = X + (size_t)(m0+row)*1024 + kb + cb*8;
      float4 f0 = *(const float4*)sa;
      float4 f1 = *(const float4*)(sa+4);
      f16x8 av;
      av[0]=(_Float16)f0.x; av[1]=(_Float16)f0.y; av[2]=(_Float16)f0.z; av[3]=(_Float16)f0.w;
      av[4]=(_Float16)f1.x; av[5]=(_Float16)f1.y; av[6]=(_Float16)f1.z; av[7]=(_Float16)f1.w;
      *(f16x8*)((char*)lds_a + row*128 + SWZ(row, cb*16)) = av;
      *(f16x8*)((char*)lds_b0 + row*128 + SWZ(row, cb*16)) =
        *(const f16x8*)(Wt + (size_t)(n0+row)*1024 + kb + cb*8);
    }
    __syncthreads();
    #pragma unroll
    for (int kk=0; kk<2; kk++){
      f16x8 af[4], b0[4];
      #pragma unroll
      for (int tm=0; tm<4; tm++){
        int row = wr*64 + tm*16 + lr;
        af[tm] = *(const f16x8*)((char*)lds_a + row*128 + SWZ(row, kk*64 + lk));
      }
      #pragma unroll
      for (int tn=0; tn<4; tn++){
        int row = wc*64 + tn*16 + lr;
        b0[tn] = *(const f16x8*)((char*)lds_b0 + row*128 + SWZ(row, kk*64 + lk));
      }
      #pragma unroll
      for (int tm=0; tm<4; tm++)
        #pragma unroll
        for (int tn=0; tn<4; tn++)
          mfma_f16(acc[tm][tn], af[tm], b0[tn]);
    }
  }
  #pragma unroll
  for (int tm=0; tm<4; tm++)
    for (int tn=0; tn<4; tn++)
      for (int r=0; r<4; r++){
        int ml = wr*64 + tm*16 + ((l>>4)<<2) + r;
        int nl = wc*64 + tn*16 + lr;
        int m = m0 + ml, np = n0 + nl;
        int t = m & 255, b = m >> 8, jg = np >> 6, nc = np & 63;
        size_t idx = (((size_t)t*64 + jg)*64 + b)*64 + nc;
        float v = (acc[tm][tn][r] + bias_c[np]) * 4096.f;
        v = fminf(fmaxf(v, -32767.f), 32767.f);
        XP[idx] = (short)(int)rintf(v);
      }
}

// ---- K3: persistent scan (flag-based cross-WG sync, fence-free) ----
// 128 WGs = 2 bg x 64 jg, 512 thr (8 waves = 2 mh x 4 nh). WG owns 32 batches x 16 j.
// Coherence design: h data and flags both move via agent-scope RELAXED atomics,
// which bypass the non-coherent per-XCD L2 (serviced at the coherence point).
// Ordering: producer-side __syncthreads() drains vmcnt (h stores ACKed =
// globally visible) before the tid0 flag store; consumer-side compiler fence
// stops reordering of post-poll loads. No L2 writeback/invalidate needed.
__global__ __launch_bounds__(512) void k_scan(
    const unsigned short* __restrict__ Wh_t,
    const short* __restrict__ XPq,
    unsigned short* __restrict__ hb0, unsigned short* __restrict__ hb1,
    unsigned int* __restrict__ flags, float* __restrict__ dout)
{
  __shared__ unsigned short lds_w[64*1024];  // 128 KB weights (swizzled)
  __shared__ unsigned short lds_h[32*256];   // 16 KB h k-quarter stage (swizzled)
  __shared__ float lds_g[32*64];             // 8 KB gate pre-activations
  __shared__ unsigned short lds_ho[32*16];   // 1 KB h out
  const int tid = threadIdx.x;
  const int wgid = blockIdx.x;
  const int bg = wgid >> 6, jg = wgid & 63;

  for (int s=0; s<16; s++){
    int idx = s*512 + tid;            // 8192 16B-chunks
    int row = idx>>7, cb = idx&127;
    *(f16x8*)((char*)lds_w + row*2048 + SWZ(row, cb*16)) =
      *(const f16x8*)(Wh_t + (size_t)(jg*64+row)*1024 + cb*8);
  }
  const int w = tid>>6, l = tid&63;
  const int mh = w>>2, nh = w&3;
  const int lr = l&15, lkb = (l>>4)*16;
  const int arow = mh*16 + lr;
  const char* abase = (const char*)lds_h + arow*512;
  const int aswz = (arow&7)<<4;
  const int wrow = nh*16 + lr;
  const char* wbase = (const char*)lds_w + wrow*2048;
  const int wswz = (wrow&7)<<4;
  const int b_l = tid>>4, jr = tid&15;
  float c = 0.f;
  __syncthreads();

  for (int t=0; t<256; t++){
    const unsigned short* cur = (t&1) ? hb1 : hb0;
    unsigned short* nxt = (t&1) ? hb0 : hb1;
    // preload this step's XP (independent of h) so latency hides under MFMA
    size_t xidx = (((size_t)t*64 + jg)*64 + (bg*32 + b_l))*64 + jr*4;
    short4 qv = *(const short4*)(XPq + xidx);
    f32x4 acc0 = {0,0,0,0}, acc1 = {0,0,0,0};
    for (int q=0; q<4; q++){
      #pragma unroll
      for (int s=0; s<4; s++){
        int idx = s*512 + tid;        // 2048 8B-chunks
        int row = idx>>6, cb = idx&63;
        unsigned long long v = __hip_atomic_load(
            (const unsigned long long*)(cur + (size_t)(bg*32+row)*1024 + q*256 + cb*4),
            __ATOMIC_RELAXED, __HIP_MEMORY_SCOPE_AGENT);
        *(unsigned long long*)((char*)lds_h + row*512 + SWZ(row, cb*8)) = v;
      }
      __syncthreads();
      #pragma unroll
      for (int kk=0; kk<8; kk++){
        f16x8 a = *(const f16x8*)(abase + ((kk*64 + lkb) ^ aswz));
        int kb = (q*8 + kk)*64 + lkb;
        f16x8 b = *(const f16x8*)(wbase + (kb ^ wswz));
        if (kk & 1) mfma_f16(acc1, a, b); else mfma_f16(acc0, a, b);
      }
      __syncthreads();
    }
    f32x4 acc = acc0 + acc1;
    {
      int row = mh*16 + ((l>>4)<<2);
      #pragma unroll
      for (int r=0; r<4; r++) lds_g[(row+r)*64 + nh*16 + lr] = acc[r];
    }
    __syncthreads();
    // elementwise: thread <-> (b_l, jr); nc = jr*4 + gate
    {
      const float INV = 1.f/4096.f;
      float p0 = lds_g[b_l*64 + jr*4 + 0] + (float)qv.x * INV;
      float p1 = lds_g[b_l*64 + jr*4 + 1] + (float)qv.y * INV;
      float p2 = lds_g[b_l*64 + jr*4 + 2] + (float)qv.z * INV;
      float p3 = lds_g[b_l*64 + jr*4 + 3] + (float)qv.w * INV;
      float f = sigm(p0), ii = sigm(p1), o = sigm(p2), g = tanh_(p3);
      c = f*c + ii*g;
      float hn = o * tanh_(c);
      lds_ho[b_l*16 + jr] = f2h(hn);
      if (t == 255) dout[(size_t)(bg*32 + b_l)*1024 + jg*16 + jr] = hn;
    }
    __syncthreads();
    if (tid < 128){
      int b = tid>>2, part = tid&3;
      unsigned long long v = ((const unsigned long long*)lds_ho)[tid];
      __hip_atomic_store((unsigned long long*)(nxt + (size_t)(bg*32+b)*1024 + jg*16 + part*4),
                         v, __ATOMIC_RELAXED, __HIP_MEMORY_SCOPE_AGENT);
    }
    __syncthreads();   // vmcnt-drain: all waves' h stores ACKed before flag
    if (t < 255){
      if (tid == 0)
        __hip_atomic_store(&flags[wgid], (unsigned)(t+1),
                           __ATOMIC_RELAXED, __HIP_MEMORY_SCOPE_AGENT);
      if (tid < 64){
        const unsigned* fp = flags + bg*64 + tid;
        while (true){
          unsigned v = __hip_atomic_load(fp, __ATOMIC_RELAXED, __HIP_MEMORY_SCOPE_AGENT);
          if (__all((int)(v > (unsigned)t))) break;
          __builtin_amdgcn_s_sleep(1);
        }
      }
      asm volatile("" ::: "memory");   // compiler-only fence: no L2 wb/inv
      __syncthreads();
    }
  }
}

extern "C" void kernel_launch(void* const* d_in, const int* in_sizes, int n_in,
                              void* d_out, int out_size, void* d_ws, size_t ws_size,
                              hipStream_t stream){
  const float* inp = (const float*)d_in[0];
  P8 pw; P4 pb;
  // gate order: 0=f 1=i 2=o 3=c
  pw.p[0] = (const float*)d_in[1];  pw.p[1] = (const float*)d_in[4];
  pw.p[2] = (const float*)d_in[7];  pw.p[3] = (const float*)d_in[10];
  pw.p[4] = (const float*)d_in[2];  pw.p[5] = (const float*)d_in[5];
  pw.p[6] = (const float*)d_in[8];  pw.p[7] = (const float*)d_in[11];
  pb.p[0] = (const float*)d_in[3];  pb.p[1] = (const float*)d_in[6];
  pb.p[2] = (const float*)d_in[9];  pb.p[3] = (const float*)d_in[12];
  float* out = (float*)d_out;
  char* ws = (char*)d_ws;

  const size_t off_flags = 0;
  const size_t off_hb0  = 4096;
  const size_t off_hb1  = off_hb0 + 131072;
  const size_t off_bias = off_hb1 + 131072;
  const size_t off_wxt  = off_bias + 16384;
  const size_t off_wht  = off_wxt + 8388608ull;    // Wx' [4096][1024] f16
  const size_t off_xp   = off_wht + 8388608ull;    // Wh' [4096][1024] f16
  const size_t xp_elems = 256ull*64*64*64;         // 67,108,864 i16
  const size_t need = off_xp + xp_elems*2;         // ~151 MB

  if (ws_size < need){
    hipMemsetAsync(d_out, 0, (size_t)out_size*4, stream);
    return;
  }

  unsigned* flags = (unsigned*)(ws + off_flags);
  unsigned short* hb0 = (unsigned short*)(ws + off_hb0);
  unsigned short* hb1 = (unsigned short*)(ws + off_hb1);
  float* bias_c = (float*)(ws + off_bias);
  unsigned short* Wxt = (unsigned short*)(ws + off_wxt);
  unsigned short* Wht = (unsigned short*)(ws + off_wht);
  short* XPq = (short*)(ws + off_xp);

  hipMemsetAsync(ws, 0, off_bias, stream);   // flags + h buffers
  k_transpose_w<<<dim3(32,32,8), dim3(32,8), 0, stream>>>(pw, Wxt, Wht);
  k_bias<<<16, 256, 0, stream>>>(pb, bias_c);
  k_gemm_xp<<<dim3(32,128), 256, 0, stream>>>(inp, Wxt, bias_c, XPq);

  void* args[6] = {(void*)&Wht, (void*)&XPq, (void*)&hb0, (void*)&hb1,
                   (void*)&flags, (void*)&out};
  hipLaunchCooperativeKernel((void*)k_scan, dim3(128), dim3(512), args, 0u, stream);
}

// Round 8
// 2004.561 us; speedup vs baseline: 3.2347x; 1.3876x over previous
//
#include <hip/hip_runtime.h>
#include <hip/hip_cooperative_groups.h>

namespace cg = cooperative_groups;

#define SWZ(row, kb) ((kb) ^ (((row)&7)<<4))

typedef _Float16 f16x8 __attribute__((ext_vector_type(8)));
typedef float f32x4 __attribute__((ext_vector_type(4)));
typedef unsigned long long ull;

__device__ inline void mfma_f16(f32x4& acc, f16x8 a, f16x8 b){
  acc = __builtin_amdgcn_mfma_f32_16x16x32_f16(a, b, acc, 0, 0, 0);
}
__device__ inline unsigned short f2h(float f){
  union{_Float16 h; unsigned short s;} u; u.h = (_Float16)f; return u.s;
}
__device__ inline float sigm(float x){
  float e = __expf(-x);
  return __builtin_amdgcn_rcpf(1.f + e);
}
__device__ inline float tanh_(float x){
  float e = __expf(2.f*x);
  return 1.f - 2.f*__builtin_amdgcn_rcpf(e + 1.f);
}

struct P8 { const float* p[8]; };
struct P4 { const float* p[4]; };

// ---- K1: transpose+convert weights -> [n'][1024] fp16 ----
// n' = (j>>4)*64 + (j&15)*4 + gate
__global__ void k_transpose_w(P8 srcs, unsigned short* __restrict__ wx_t,
                              unsigned short* __restrict__ wh_t){
  __shared__ float tile[32][33];
  int z = blockIdx.z;               // which*4 + gate
  int gate = z & 3, which = z >> 2;
  const float* src = srcs.p[z];
  unsigned short* dst = which ? wh_t : wx_t;
  int k0 = blockIdx.x*32, j0 = blockIdx.y*32;
  int tx = threadIdx.x, ty = threadIdx.y;   // 32 x 8
  #pragma unroll
  for (int s=0; s<4; s++){
    int k = ty*4 + s;
    tile[k][tx] = src[(size_t)(k0+k)*1024 + j0 + tx];
  }
  __syncthreads();
  #pragma unroll
  for (int s=0; s<4; s++){
    int j = j0 + ty*4 + s;
    int np = ((j>>4)<<6) + ((j&15)<<2) + gate;
    dst[(size_t)np*1024 + k0 + tx] = f2h(tile[tx][ty*4+s]);
  }
}

// ---- K1b: combined bias[n'] ----
__global__ void k_bias(P4 bs, float* __restrict__ bias_c){
  int np = blockIdx.x*blockDim.x + threadIdx.x;
  if (np >= 4096) return;
  int gate = np & 3;
  int j = ((np>>6)<<4) + ((np>>2)&15);
  bias_c[np] = bs.p[gate][j];
}

// ---- K2: phase-1 GEMM  XP = fp16(x) @ fp16(Wx) + bias ----
// out: XP[t][jg][b][nc] as i16 fixed-point (value * 4096)
__global__ __launch_bounds__(256) void k_gemm_xp(
    const float* __restrict__ X,
    const unsigned short* __restrict__ Wt,
    const float* __restrict__ bias_c,
    short* __restrict__ XP)
{
  __shared__ unsigned short lds_a[128*64];
  __shared__ unsigned short lds_b0[128*64];
  const int tid = threadIdx.x;
  const int m0 = blockIdx.y*128, n0 = blockIdx.x*128;
  const int w = tid>>6, l = tid&63;
  const int wr = w>>1, wc = w&1;
  const int lr = l&15, lk = (l>>4)*16;
  f32x4 acc[4][4] = {};
  for (int kt=0; kt<16; kt++){
    __syncthreads();
    const int kb = kt*64;
    #pragma unroll
    for (int c4=0; c4<4; c4++){
      int idx = c4*256 + tid;
      int row = idx>>3, cb = idx&7;
      const float* sa = X + (size_t)(m0+row)*1024 + kb + cb*8;
      float4 f0 = *(const float4*)sa;
      float4 f1 = *(const float4*)(sa+4);
      f16x8 av;
      av[0]=(_Float16)f0.x; av[1]=(_Float16)f0.y; av[2]=(_Float16)f0.z; av[3]=(_Float16)f0.w;
      av[4]=(_Float16)f1.x; av[5]=(_Float16)f1.y; av[6]=(_Float16)f1.z; av[7]=(_Float16)f1.w;
      *(f16x8*)((char*)lds_a + row*128 + SWZ(row, cb*16)) = av;
      *(f16x8*)((char*)lds_b0 + row*128 + SWZ(row, cb*16)) =
        *(const f16x8*)(Wt + (size_t)(n0+row)*1024 + kb + cb*8);
    }
    __syncthreads();
    #pragma unroll
    for (int kk=0; kk<2; kk++){
      f16x8 af[4], b0[4];
      #pragma unroll
      for (int tm=0; tm<4; tm++){
        int row = wr*64 + tm*16 + lr;
        af[tm] = *(const f16x8*)((char*)lds_a + row*128 + SWZ(row, kk*64 + lk));
      }
      #pragma unroll
      for (int tn=0; tn<4; tn++){
        int row = wc*64 + tn*16 + lr;
        b0[tn] = *(const f16x8*)((char*)lds_b0 + row*128 + SWZ(row, kk*64 + lk));
      }
      #pragma unroll
      for (int tm=0; tm<4; tm++)
        #pragma unroll
        for (int tn=0; tn<4; tn++)
          mfma_f16(acc[tm][tn], af[tm], b0[tn]);
    }
  }
  #pragma unroll
  for (int tm=0; tm<4; tm++)
    for (int tn=0; tn<4; tn++)
      for (int r=0; r<4; r++){
        int ml = wr*64 + tm*16 + ((l>>4)<<2) + r;
        int nl = wc*64 + tn*16 + lr;
        int m = m0 + ml, np = n0 + nl;
        int t = m & 255, b = m >> 8, jg = np >> 6, nc = np & 63;
        size_t idx = (((size_t)t*64 + jg)*64 + b)*64 + nc;
        float v = (acc[tm][tn][r] + bias_c[np]) * 4096.f;
        v = fminf(fmaxf(v, -32767.f), 32767.f);
        XP[idx] = (short)(int)rintf(v);
      }
}

// ---- K3: persistent scan (flag-based cross-WG sync, fence-free, reg-staged h) ----
// 128 WGs = 2 bg x 64 jg, 512 thr (8 waves = 2 mh x 4 nh). WG owns 32 batches x 16 j.
// h and flags move via agent-scope RELAXED atomics (coherence-point serviced;
// bypass non-coherent per-XCD L2). Producer: __syncthreads() vmcnt-drain before
// flag store. Consumer: compiler fence after poll. No L2 wb/inv (round-7 win).
// Round-8: all 16 h-loads issued once per step into regs; per-quarter global
// latency now overlaps previous quarter's ds_write+MFMA.
__global__ __launch_bounds__(512) void k_scan(
    const unsigned short* __restrict__ Wh_t,
    const short* __restrict__ XPq,
    unsigned short* __restrict__ hb0, unsigned short* __restrict__ hb1,
    unsigned int* __restrict__ flags, float* __restrict__ dout)
{
  __shared__ unsigned short lds_w[64*1024];  // 128 KB weights (swizzled)
  __shared__ unsigned short lds_h[32*256];   // 16 KB h k-quarter stage (swizzled)
  __shared__ float lds_g[32*64];             // 8 KB gate pre-activations
  const int tid = threadIdx.x;
  const int wgid = blockIdx.x;
  const int bg = wgid >> 6, jg = wgid & 63;

  for (int s=0; s<16; s++){
    int idx = s*512 + tid;            // 8192 16B-chunks
    int row = idx>>7, cb = idx&127;
    *(f16x8*)((char*)lds_w + row*2048 + SWZ(row, cb*16)) =
      *(const f16x8*)(Wh_t + (size_t)(jg*64+row)*1024 + cb*8);
  }
  const int w = tid>>6, l = tid&63;
  const int mh = w>>2, nh = w&3;
  const int lr = l&15, lkb = (l>>4)*16;
  const int arow = mh*16 + lr;
  const char* abase = (const char*)lds_h + arow*512;
  const int aswz = (arow&7)<<4;
  const int wrow = nh*16 + lr;
  const char* wbase = (const char*)lds_w + wrow*2048;
  const int wswz = (wrow&7)<<4;
  const int b_l = tid>>4, jr = tid&15;
  // h-load/ds_write geometry (same for every quarter)
  const int hrow = tid>>6;            // via idx = s*512+tid: row=(s*512+tid)>>6
  float c = 0.f;
  __syncthreads();

  for (int t=0; t<256; t++){
    const unsigned short* cur = (t&1) ? hb1 : hb0;
    unsigned short* nxt = (t&1) ? hb0 : hb1;
    // preload this step's XP (independent of h) so latency hides under MFMA
    size_t xidx = (((size_t)t*64 + jg)*64 + (bg*32 + b_l))*64 + jr*4;
    short4 qv = *(const short4*)(XPq + xidx);

    // issue ALL h loads for the step (16 x 8B per thread, agent-relaxed)
    ull hv[16];
    #pragma unroll
    for (int q=0; q<4; q++)
      #pragma unroll
      for (int s=0; s<4; s++){
        int idx = s*512 + tid;
        int row = idx>>6, cb = idx&63;
        hv[q*4+s] = __hip_atomic_load(
            (const ull*)(cur + (size_t)(bg*32+row)*1024 + q*256 + cb*4),
            __ATOMIC_RELAXED, __HIP_MEMORY_SCOPE_AGENT);
      }

    f32x4 acc0 = {0,0,0,0}, acc1 = {0,0,0,0};
    #pragma unroll
    for (int q=0; q<4; q++){
      #pragma unroll
      for (int s=0; s<4; s++){
        int idx = s*512 + tid;
        int row = idx>>6, cb = idx&63;
        *(ull*)((char*)lds_h + row*512 + SWZ(row, cb*8)) = hv[q*4+s];
      }
      __syncthreads();
      #pragma unroll
      for (int kk=0; kk<8; kk++){
        f16x8 a = *(const f16x8*)(abase + ((kk*64 + lkb) ^ aswz));
        int kb = (q*8 + kk)*64 + lkb;
        f16x8 b = *(const f16x8*)(wbase + (kb ^ wswz));
        if (kk & 1) mfma_f16(acc1, a, b); else mfma_f16(acc0, a, b);
      }
      __syncthreads();
    }
    f32x4 acc = acc0 + acc1;
    {
      int row = mh*16 + ((l>>4)<<2);
      #pragma unroll
      for (int r=0; r<4; r++) lds_g[(row+r)*64 + nh*16 + lr] = acc[r];
    }
    __syncthreads();
    // elementwise: thread <-> (b_l, jr); nc = jr*4 + gate; direct 2B h store
    {
      const float INV = 1.f/4096.f;
      float p0 = lds_g[b_l*64 + jr*4 + 0] + (float)qv.x * INV;
      float p1 = lds_g[b_l*64 + jr*4 + 1] + (float)qv.y * INV;
      float p2 = lds_g[b_l*64 + jr*4 + 2] + (float)qv.z * INV;
      float p3 = lds_g[b_l*64 + jr*4 + 3] + (float)qv.w * INV;
      float f = sigm(p0), ii = sigm(p1), o = sigm(p2), g = tanh_(p3);
      c = f*c + ii*g;
      float hn = o * tanh_(c);
      __hip_atomic_store(nxt + (size_t)(bg*32 + b_l)*1024 + jg*16 + jr,
                         f2h(hn), __ATOMIC_RELAXED, __HIP_MEMORY_SCOPE_AGENT);
      if (t == 255) dout[(size_t)(bg*32 + b_l)*1024 + jg*16 + jr] = hn;
    }
    __syncthreads();   // vmcnt-drain: all waves' h stores ACKed before flag
    if (t < 255){
      if (tid == 0)
        __hip_atomic_store(&flags[wgid], (unsigned)(t+1),
                           __ATOMIC_RELAXED, __HIP_MEMORY_SCOPE_AGENT);
      if (tid < 64){
        const unsigned* fp = flags + bg*64 + tid;
        while (true){
          unsigned v = __hip_atomic_load(fp, __ATOMIC_RELAXED, __HIP_MEMORY_SCOPE_AGENT);
          if (__all((int)(v > (unsigned)t))) break;
        }
      }
      asm volatile("" ::: "memory");   // compiler-only fence: no L2 wb/inv
      __syncthreads();
    }
  }
}

extern "C" void kernel_launch(void* const* d_in, const int* in_sizes, int n_in,
                              void* d_out, int out_size, void* d_ws, size_t ws_size,
                              hipStream_t stream){
  const float* inp = (const float*)d_in[0];
  P8 pw; P4 pb;
  // gate order: 0=f 1=i 2=o 3=c
  pw.p[0] = (const float*)d_in[1];  pw.p[1] = (const float*)d_in[4];
  pw.p[2] = (const float*)d_in[7];  pw.p[3] = (const float*)d_in[10];
  pw.p[4] = (const float*)d_in[2];  pw.p[5] = (const float*)d_in[5];
  pw.p[6] = (const float*)d_in[8];  pw.p[7] = (const float*)d_in[11];
  pb.p[0] = (const float*)d_in[3];  pb.p[1] = (const float*)d_in[6];
  pb.p[2] = (const float*)d_in[9];  pb.p[3] = (const float*)d_in[12];
  float* out = (float*)d_out;
  char* ws = (char*)d_ws;

  const size_t off_flags = 0;
  const size_t off_hb0  = 4096;
  const size_t off_hb1  = off_hb0 + 131072;
  const size_t off_bias = off_hb1 + 131072;
  const size_t off_wxt  = off_bias + 16384;
  const size_t off_wht  = off_wxt + 8388608ull;    // Wx' [4096][1024] f16
  const size_t off_xp   = off_wht + 8388608ull;    // Wh' [4096][1024] f16
  const size_t xp_elems = 256ull*64*64*64;         // 67,108,864 i16
  const size_t need = off_xp + xp_elems*2;         // ~151 MB

  if (ws_size < need){
    hipMemsetAsync(d_out, 0, (size_t)out_size*4, stream);
    return;
  }

  unsigned* flags = (unsigned*)(ws + off_flags);
  unsigned short* hb0 = (unsigned short*)(ws + off_hb0);
  unsigned short* hb1 = (unsigned short*)(ws + off_hb1);
  float* bias_c = (float*)(ws + off_bias);
  unsigned short* Wxt = (unsigned short*)(ws + off_wxt);
  unsigned short* Wht = (unsigned short*)(ws + off_wht);
  short* XPq = (short*)(ws + off_xp);

  hipMemsetAsync(ws, 0, off_bias, stream);   // flags + h buffers
  k_transpose_w<<<dim3(32,32,8), dim3(32,8), 0, stream>>>(pw, Wxt, Wht);
  k_bias<<<16, 256, 0, stream>>>(pb, bias_c);
  k_gemm_xp<<<dim3(32,128), 256, 0, stream>>>(inp, Wxt, bias_c, XPq);

  void* args[6] = {(void*)&Wht, (void*)&XPq, (void*)&hb0, (void*)&hb1,
                   (void*)&flags, (void*)&out};
  hipLaunchCooperativeKernel((void*)k_scan, dim3(128), dim3(512), args, 0u, stream);
}